// Round 4
// baseline (392.078 us; speedup 1.0000x reference)
//
#include <hip/hip_runtime.h>
#include <hip/hip_bf16.h>

// Shapes fixed by setup_inputs(): B=2, C=128, H=256, W=448, stride=1.
#define BB 2
#define CC 128
#define HH 256
#define WW 448
#define KK 49
#define HWSZ (HH * WW)
#define PW 456  // padded width of wt: px = x+4, x in [-4, 452)

#define WT_BYTES ((size_t)BB * HH * PW * CC * 2)      // 59,768,832
#define TWT_BYTES ((size_t)BB * HH * WW * CC * 2)     // 58,720,256
#define WS_NEED (WT_BYTES + TWT_BYTES)

typedef __attribute__((ext_vector_type(8))) short bf16x8;
typedef __attribute__((ext_vector_type(4))) float f32x4;
typedef __attribute__((ext_vector_type(8))) unsigned short u16x8;

static __device__ __forceinline__ short f2bf(float v) {
  __hip_bfloat16 h = __float2bfloat16(v);
  return *reinterpret_cast<short*>(&h);
}
static __device__ __forceinline__ float bf2f(unsigned short u) {
  unsigned int x = ((unsigned int)u) << 16;
  return __uint_as_float(x);
}

// ---------------- Kernel 0: zero the x-padding borders of wt ----------------
__global__ __launch_bounds__(256) void border_kernel(__hip_bfloat16* wt) {
  int i = blockIdx.x * 256 + threadIdx.x;  // 65536
  int by = i >> 7;
  int r = i & 127;
  int ps = r >> 4;
  int c16 = r & 15;
  int px = (ps < 4) ? ps : (448 + ps);
  u16x8 z = {0, 0, 0, 0, 0, 0, 0, 0};
  *(u16x8*)((char*)wt + ((size_t)((size_t)by * PW + px) * CC + c16 * 8) * 2) = z;
}

// ---------------- Kernel T: transpose tenTwo [c][p] f32 -> two_t [p][c] bf16
// Tile: 128 channels x 32 pixels. p = y*WW+x is contiguous; 448%32==0 so
// tiles never cross rows.
__global__ __launch_bounds__(256) void transpose_kernel(
    const float* __restrict__ two, __hip_bfloat16* __restrict__ two_t) {
  __shared__ float lds[128 * 33];
  int bid = blockIdx.x;            // BB * 3584
  int b = bid / (HWSZ / 32);
  int tile = bid - b * (HWSZ / 32);
  int P0 = tile * 32;

  const float* src = two + (size_t)b * CC * HWSZ + P0;
  int t = threadIdx.x;
  int bc = t >> 3;   // 0..31
  int f = t & 7;     // 0..7 (float4 index within 32-float row)
#pragma unroll
  for (int k = 0; k < 4; ++k) {
    int c = bc + k * 32;
    float4 v = *(const float4*)(src + (size_t)c * HWSZ + f * 4);
    float* d = &lds[c * 33 + f * 4];
    d[0] = v.x; d[1] = v.y; d[2] = v.z; d[3] = v.w;
  }
  __syncthreads();

  int q = t & 7;     // c-chunk of 16
  int pl = t >> 3;   // 0..31 pixel
  int cs = q * 16;
  u16x8 pk0, pk1;
#pragma unroll
  for (int j = 0; j < 8; ++j)
    pk0[j] = (unsigned short)f2bf(lds[(cs + j) * 33 + pl]);
#pragma unroll
  for (int j = 0; j < 8; ++j)
    pk1[j] = (unsigned short)f2bf(lds[(cs + 8 + j) * 33 + pl]);
  char* dst = (char*)two_t + ((size_t)((size_t)b * HWSZ + P0 + pl) * CC + cs) * 2;
  *(u16x8*)dst = pk0;
  *(u16x8*)(dst + 16) = pk1;
}

// ---------------- Kernel 1 (fast): gather from two_t [p][c] bf16 -----------
__global__ __launch_bounds__(256) void warp_fast(
    const __hip_bfloat16* __restrict__ two_t, const float* __restrict__ flow,
    __hip_bfloat16* __restrict__ wt) {
  int idx = blockIdx.x * 256 + threadIdx.x;
  if (idx >= BB * HWSZ) return;
  int x = idx % WW;
  int y = (idx / WW) % HH;
  int b = idx / HWSZ;

  float fx = flow[(b * 2 + 0) * HWSZ + y * WW + x] * 2.5f;
  float fy = flow[(b * 2 + 1) * HWSZ + y * WW + x] * 2.5f;
  float px = (float)x + fx;
  float py = (float)y + fy;
  float x0f = floorf(px), y0f = floorf(py);
  int x0 = (int)x0f, y0 = (int)y0f;
  int x1 = x0 + 1, y1 = y0 + 1;
  float wx1 = px - x0f, wx0 = 1.0f - wx1;
  float wy1 = py - y0f, wy0 = 1.0f - wy1;
  bool vx0 = (x0 >= 0) && (x0 < WW);
  bool vx1 = (x1 >= 0) && (x1 < WW);
  bool vy0 = (y0 >= 0) && (y0 < HH);
  bool vy1 = (y1 >= 0) && (y1 < HH);
  float w00 = (vx0 && vy0) ? wx0 * wy0 : 0.0f;
  float w01 = (vx1 && vy0) ? wx1 * wy0 : 0.0f;
  float w10 = (vx0 && vy1) ? wx0 * wy1 : 0.0f;
  float w11 = (vx1 && vy1) ? wx1 * wy1 : 0.0f;
  int cx0 = min(max(x0, 0), WW - 1);
  int cx1 = min(max(x1, 0), WW - 1);
  int cy0 = min(max(y0, 0), HH - 1);
  int cy1 = min(max(y1, 0), HH - 1);

  const u16x8* p00 = (const u16x8*)(two_t + ((size_t)(b * HH + cy0) * WW + cx0) * CC);
  const u16x8* p01 = (const u16x8*)(two_t + ((size_t)(b * HH + cy0) * WW + cx1) * CC);
  const u16x8* p10 = (const u16x8*)(two_t + ((size_t)(b * HH + cy1) * WW + cx0) * CC);
  const u16x8* p11 = (const u16x8*)(two_t + ((size_t)(b * HH + cy1) * WW + cx1) * CC);
  u16x8* wo = (u16x8*)(wt + ((size_t)(b * HH + y) * PW + x + 4) * CC);

#pragma unroll 4
  for (int j = 0; j < 16; ++j) {
    u16x8 a = p00[j], bb_ = p01[j], c = p10[j], d = p11[j];
    u16x8 pk;
#pragma unroll
    for (int e = 0; e < 8; ++e) {
      float v = w00 * bf2f((unsigned short)a[e]) +
                w01 * bf2f((unsigned short)bb_[e]) +
                w10 * bf2f((unsigned short)c[e]) +
                w11 * bf2f((unsigned short)d[e]);
      pk[e] = (unsigned short)f2bf(v);
    }
    wo[j] = pk;
  }
}

// ---------------- Kernel 1 (fallback): gather f32 planes directly -----------
__global__ __launch_bounds__(256) void warp_fallback(
    const float* __restrict__ two, const float* __restrict__ flow,
    __hip_bfloat16* __restrict__ wt) {
  int idx = blockIdx.x * 256 + threadIdx.x;
  if (idx >= BB * HWSZ) return;
  int x = idx % WW;
  int y = (idx / WW) % HH;
  int b = idx / HWSZ;

  float fx = flow[(b * 2 + 0) * HWSZ + y * WW + x] * 2.5f;
  float fy = flow[(b * 2 + 1) * HWSZ + y * WW + x] * 2.5f;
  float px = (float)x + fx;
  float py = (float)y + fy;
  float x0f = floorf(px), y0f = floorf(py);
  int x0 = (int)x0f, y0 = (int)y0f;
  int x1 = x0 + 1, y1 = y0 + 1;
  float wx1 = px - x0f, wx0 = 1.0f - wx1;
  float wy1 = py - y0f, wy0 = 1.0f - wy1;
  bool vx0 = (x0 >= 0) && (x0 < WW);
  bool vx1 = (x1 >= 0) && (x1 < WW);
  bool vy0 = (y0 >= 0) && (y0 < HH);
  bool vy1 = (y1 >= 0) && (y1 < HH);
  float w00 = (vx0 && vy0) ? wx0 * wy0 : 0.0f;
  float w01 = (vx1 && vy0) ? wx1 * wy0 : 0.0f;
  float w10 = (vx0 && vy1) ? wx0 * wy1 : 0.0f;
  float w11 = (vx1 && vy1) ? wx1 * wy1 : 0.0f;
  int cx0 = min(max(x0, 0), WW - 1);
  int cx1 = min(max(x1, 0), WW - 1);
  int cy0 = min(max(y0, 0), HH - 1);
  int cy1 = min(max(y1, 0), HH - 1);
  int o00 = cy0 * WW + cx0;
  int o01 = cy0 * WW + cx1;
  int o10 = cy1 * WW + cx0;
  int o11 = cy1 * WW + cx1;

  const float* p = two + (size_t)b * CC * HWSZ;
  char* wo = (char*)wt + ((size_t)((size_t)(b * HH + y) * PW) + x + 4) * CC * 2;
#pragma unroll 4
  for (int j = 0; j < 16; ++j) {
    u16x8 pk;
#pragma unroll
    for (int jj = 0; jj < 8; ++jj) {
      int c = j * 8 + jj;
      const float* pc = p + (size_t)c * HWSZ;
      float v = w00 * pc[o00] + w01 * pc[o01] + w10 * pc[o10] + w11 * pc[o11];
      pk[jj] = (unsigned short)f2bf(v);
    }
    *(u16x8*)(wo + j * 16) = pk;
  }
}

// ---------------- Kernel 2: correlation via MFMA (unchanged from R3) --------
__global__ __launch_bounds__(256) void corr_kernel(
    const float* __restrict__ one, const __hip_bfloat16* __restrict__ wt,
    float* __restrict__ out) {
  int bid = blockIdx.x;                     // 3584 = 8 * 448
  int wgid = (bid & 7) * 448 + (bid >> 3);  // XCD swizzle (bijective)
  int b = wgid / 1792;
  int rem = wgid - b * 1792;
  int xt = rem >> 6;
  int yg = rem & 63;
  int w = threadIdx.x >> 6;
  int l = threadIdx.x & 63;
  int lp = l & 15;
  int lg = l >> 4;
  int y = yg * 4 + w;
  int X0 = xt * 16;

  const float* Abase = one + ((size_t)(b * CC) * HH + y) * WW + X0 + lp;
  int pos1 = (lp + 16 < 21) ? (lp + 16) : 21;
  const char* Bb = (const char*)wt + (size_t)(b * HH) * PW * CC * 2;
  size_t pxo0 = (size_t)(X0 + 1 + lp) * CC * 2;
  size_t pxo1 = (size_t)(X0 + 1 + pos1) * CC * 2;

  f32x4 acc[7][2] = {};

#pragma unroll
  for (int t = 0; t < 4; ++t) {
    bf16x8 a;
#pragma unroll
    for (int j = 0; j < 8; ++j) {
      float v = Abase[(size_t)(t * 32 + lg * 8 + j) * HWSZ];
      a[j] = f2bf(v);
    }
    size_t coff = (size_t)(t * 32 + lg * 8) * 2;
#pragma unroll
    for (int dj = 0; dj < 7; ++dj) {
      int yy = y + dj - 3;
      if (yy < 0 || yy >= HH) continue;  // wave-uniform
      const char* rb = Bb + (size_t)yy * PW * CC * 2 + coff;
      bf16x8 b0 = *(const bf16x8*)(rb + pxo0);
      bf16x8 b1 = *(const bf16x8*)(rb + pxo1);
      acc[dj][0] =
          __builtin_amdgcn_mfma_f32_16x16x32_bf16(a, b0, acc[dj][0], 0, 0, 0);
      acc[dj][1] =
          __builtin_amdgcn_mfma_f32_16x16x32_bf16(a, b1, acc[dj][1], 0, 0, 0);
    }
  }

  float* obase = out + ((size_t)(b * KK) * HH + y) * WW + X0;
#pragma unroll
  for (int dj = 0; dj < 7; ++dj) {
    float* od = obase + (size_t)(dj * 7) * HWSZ;
#pragma unroll
    for (int nt = 0; nt < 2; ++nt) {
      int post = lp + 16 * nt;
#pragma unroll
      for (int r = 0; r < 4; ++r) {
        int xlc = 4 * lg + r;
        int di = post - xlc;
        float v = acc[dj][nt][r] * (1.0f / 128.0f);
        v = (v > 0.0f) ? v : 0.1f * v;
        if (di >= 0 && di <= 6) od[(size_t)di * HWSZ + xlc] = v;
      }
    }
  }
}

// ---------------- launch ----------------------------------------------------
extern "C" void kernel_launch(void* const* d_in, const int* in_sizes, int n_in,
                              void* d_out, int out_size, void* d_ws,
                              size_t ws_size, hipStream_t stream) {
  const float* tenOne = (const float*)d_in[0];
  const float* tenTwo = (const float*)d_in[1];
  const float* tenFlow = (const float*)d_in[2];

  __hip_bfloat16* wt = (__hip_bfloat16*)d_ws;
  border_kernel<<<256, 256, 0, stream>>>(wt);

  if (ws_size >= WS_NEED) {
    __hip_bfloat16* two_t = (__hip_bfloat16*)((char*)d_ws + WT_BYTES);
    transpose_kernel<<<BB * (HWSZ / 32), 256, 0, stream>>>(tenTwo, two_t);
    int blocks = (BB * HWSZ + 255) / 256;
    warp_fast<<<blocks, 256, 0, stream>>>(two_t, tenFlow, wt);
  } else {
    int blocks = (BB * HWSZ + 255) / 256;
    warp_fallback<<<blocks, 256, 0, stream>>>(tenTwo, tenFlow, wt);
  }
  corr_kernel<<<3584, 256, 0, stream>>>(tenOne, wt, (float*)d_out);
}

// Round 5
// 268.617 us; speedup vs baseline: 1.4596x; 1.4596x over previous
//
#include <hip/hip_runtime.h>
#include <hip/hip_bf16.h>

// Shapes fixed by setup_inputs(): B=2, C=128, H=256, W=448, stride=1.
#define BB 2
#define CC 128
#define HH 256
#define WW 448
#define KK 49
#define HWSZ (HH * WW)
#define PW 456  // padded width of wt: px = x+4, x in [-4, 452)

#define WT_BYTES ((size_t)BB * HH * PW * CC * 2)      // 59,768,832
#define TWT_BYTES ((size_t)BB * HH * WW * CC * 2)     // 58,720,256
#define WS_NEED (WT_BYTES + TWT_BYTES)

typedef __attribute__((ext_vector_type(8))) short bf16x8;
typedef __attribute__((ext_vector_type(4))) float f32x4;
typedef __attribute__((ext_vector_type(8))) unsigned short u16x8;

static __device__ __forceinline__ short f2bf(float v) {
  __hip_bfloat16 h = __float2bfloat16(v);
  return *reinterpret_cast<short*>(&h);
}
static __device__ __forceinline__ float bf2f(unsigned short u) {
  unsigned int x = ((unsigned int)u) << 16;
  return __uint_as_float(x);
}

// ---------------- Kernel 0: zero the x-padding borders of wt ----------------
__global__ __launch_bounds__(256) void border_kernel(__hip_bfloat16* wt) {
  int i = blockIdx.x * 256 + threadIdx.x;  // 65536
  int by = i >> 7;
  int r = i & 127;
  int ps = r >> 4;
  int c16 = r & 15;
  int px = (ps < 4) ? ps : (448 + ps);
  u16x8 z = {0, 0, 0, 0, 0, 0, 0, 0};
  *(u16x8*)((char*)wt + ((size_t)((size_t)by * PW + px) * CC + c16 * 8) * 2) = z;
}

// ---------------- Kernel T: transpose tenTwo [c][p] f32 -> two_t [p][c] bf16
__global__ __launch_bounds__(256) void transpose_kernel(
    const float* __restrict__ two, __hip_bfloat16* __restrict__ two_t) {
  __shared__ float lds[128 * 33];
  int bid = blockIdx.x;            // BB * 3584
  int b = bid / (HWSZ / 32);
  int tile = bid - b * (HWSZ / 32);
  int P0 = tile * 32;

  const float* src = two + (size_t)b * CC * HWSZ + P0;
  int t = threadIdx.x;
  int bc = t >> 3;   // 0..31
  int f = t & 7;     // 0..7
#pragma unroll
  for (int k = 0; k < 4; ++k) {
    int c = bc + k * 32;
    float4 v = *(const float4*)(src + (size_t)c * HWSZ + f * 4);
    float* d = &lds[c * 33 + f * 4];
    d[0] = v.x; d[1] = v.y; d[2] = v.z; d[3] = v.w;
  }
  __syncthreads();

  int q = t & 7;     // c-chunk of 16
  int pl = t >> 3;   // 0..31 pixel
  int cs = q * 16;
  u16x8 pk0, pk1;
#pragma unroll
  for (int j = 0; j < 8; ++j)
    pk0[j] = (unsigned short)f2bf(lds[(cs + j) * 33 + pl]);
#pragma unroll
  for (int j = 0; j < 8; ++j)
    pk1[j] = (unsigned short)f2bf(lds[(cs + 8 + j) * 33 + pl]);
  char* dst = (char*)two_t + ((size_t)((size_t)b * HWSZ + P0 + pl) * CC + cs) * 2;
  *(u16x8*)dst = pk0;
  *(u16x8*)(dst + 16) = pk1;
}

// ---------------- Kernel 1 (fast): gather from two_t [p][c] bf16 -----------
// One block per (b, y) row, 448 threads. Chunked XCD swizzle: each XCD owns
// 64 contiguous rows so its L2 holds the corner working set (gather reuse).
__global__ __launch_bounds__(448) void warp_fast(
    const __hip_bfloat16* __restrict__ two_t, const float* __restrict__ flow,
    __hip_bfloat16* __restrict__ wt) {
  int wg = (blockIdx.x & 7) * 64 + (blockIdx.x >> 3);  // 512 blocks, bijective
  int b = wg >> 8;
  int y = wg & 255;
  int x = threadIdx.x;  // 0..447

  float fx = flow[(b * 2 + 0) * HWSZ + y * WW + x] * 2.5f;
  float fy = flow[(b * 2 + 1) * HWSZ + y * WW + x] * 2.5f;
  float px = (float)x + fx;
  float py = (float)y + fy;
  float x0f = floorf(px), y0f = floorf(py);
  int x0 = (int)x0f, y0 = (int)y0f;
  int x1 = x0 + 1, y1 = y0 + 1;
  float wx1 = px - x0f, wx0 = 1.0f - wx1;
  float wy1 = py - y0f, wy0 = 1.0f - wy1;
  bool vx0 = (x0 >= 0) && (x0 < WW);
  bool vx1 = (x1 >= 0) && (x1 < WW);
  bool vy0 = (y0 >= 0) && (y0 < HH);
  bool vy1 = (y1 >= 0) && (y1 < HH);
  float w00 = (vx0 && vy0) ? wx0 * wy0 : 0.0f;
  float w01 = (vx1 && vy0) ? wx1 * wy0 : 0.0f;
  float w10 = (vx0 && vy1) ? wx0 * wy1 : 0.0f;
  float w11 = (vx1 && vy1) ? wx1 * wy1 : 0.0f;
  int cx0 = min(max(x0, 0), WW - 1);
  int cx1 = min(max(x1, 0), WW - 1);
  int cy0 = min(max(y0, 0), HH - 1);
  int cy1 = min(max(y1, 0), HH - 1);

  const u16x8* p00 = (const u16x8*)(two_t + ((size_t)(b * HH + cy0) * WW + cx0) * CC);
  const u16x8* p01 = (const u16x8*)(two_t + ((size_t)(b * HH + cy0) * WW + cx1) * CC);
  const u16x8* p10 = (const u16x8*)(two_t + ((size_t)(b * HH + cy1) * WW + cx0) * CC);
  const u16x8* p11 = (const u16x8*)(two_t + ((size_t)(b * HH + cy1) * WW + cx1) * CC);
  u16x8* wo = (u16x8*)(wt + ((size_t)(b * HH + y) * PW + x + 4) * CC);

#pragma unroll 4
  for (int j = 0; j < 16; ++j) {
    u16x8 a = p00[j], bb_ = p01[j], c = p10[j], d = p11[j];
    u16x8 pk;
#pragma unroll
    for (int e = 0; e < 8; ++e) {
      float v = w00 * bf2f((unsigned short)a[e]) +
                w01 * bf2f((unsigned short)bb_[e]) +
                w10 * bf2f((unsigned short)c[e]) +
                w11 * bf2f((unsigned short)d[e]);
      pk[e] = (unsigned short)f2bf(v);
    }
    wo[j] = pk;
  }
}

// ---------------- Kernel 1 (fallback): gather f32 planes directly -----------
__global__ __launch_bounds__(256) void warp_fallback(
    const float* __restrict__ two, const float* __restrict__ flow,
    __hip_bfloat16* __restrict__ wt) {
  int idx = blockIdx.x * 256 + threadIdx.x;
  if (idx >= BB * HWSZ) return;
  int x = idx % WW;
  int y = (idx / WW) % HH;
  int b = idx / HWSZ;

  float fx = flow[(b * 2 + 0) * HWSZ + y * WW + x] * 2.5f;
  float fy = flow[(b * 2 + 1) * HWSZ + y * WW + x] * 2.5f;
  float px = (float)x + fx;
  float py = (float)y + fy;
  float x0f = floorf(px), y0f = floorf(py);
  int x0 = (int)x0f, y0 = (int)y0f;
  int x1 = x0 + 1, y1 = y0 + 1;
  float wx1 = px - x0f, wx0 = 1.0f - wx1;
  float wy1 = py - y0f, wy0 = 1.0f - wy1;
  bool vx0 = (x0 >= 0) && (x0 < WW);
  bool vx1 = (x1 >= 0) && (x1 < WW);
  bool vy0 = (y0 >= 0) && (y0 < HH);
  bool vy1 = (y1 >= 0) && (y1 < HH);
  float w00 = (vx0 && vy0) ? wx0 * wy0 : 0.0f;
  float w01 = (vx1 && vy0) ? wx1 * wy0 : 0.0f;
  float w10 = (vx0 && vy1) ? wx0 * wy1 : 0.0f;
  float w11 = (vx1 && vy1) ? wx1 * wy1 : 0.0f;
  int cx0 = min(max(x0, 0), WW - 1);
  int cx1 = min(max(x1, 0), WW - 1);
  int cy0 = min(max(y0, 0), HH - 1);
  int cy1 = min(max(y1, 0), HH - 1);
  int o00 = cy0 * WW + cx0;
  int o01 = cy0 * WW + cx1;
  int o10 = cy1 * WW + cx0;
  int o11 = cy1 * WW + cx1;

  const float* p = two + (size_t)b * CC * HWSZ;
  char* wo = (char*)wt + ((size_t)((size_t)(b * HH + y) * PW) + x + 4) * CC * 2;
#pragma unroll 4
  for (int j = 0; j < 16; ++j) {
    u16x8 pk;
#pragma unroll
    for (int jj = 0; jj < 8; ++jj) {
      int c = j * 8 + jj;
      const float* pc = p + (size_t)c * HWSZ;
      float v = w00 * pc[o00] + w01 * pc[o01] + w10 * pc[o10] + w11 * pc[o11];
      pk[jj] = (unsigned short)f2bf(v);
    }
    *(u16x8*)(wo + j * 16) = pk;
  }
}

// ---------------- Kernel 2: correlation via MFMA (unchanged) ----------------
__global__ __launch_bounds__(256) void corr_kernel(
    const float* __restrict__ one, const __hip_bfloat16* __restrict__ wt,
    float* __restrict__ out) {
  int bid = blockIdx.x;                     // 3584 = 8 * 448
  int wgid = (bid & 7) * 448 + (bid >> 3);  // XCD swizzle (bijective)
  int b = wgid / 1792;
  int rem = wgid - b * 1792;
  int xt = rem >> 6;
  int yg = rem & 63;
  int w = threadIdx.x >> 6;
  int l = threadIdx.x & 63;
  int lp = l & 15;
  int lg = l >> 4;
  int y = yg * 4 + w;
  int X0 = xt * 16;

  const float* Abase = one + ((size_t)(b * CC) * HH + y) * WW + X0 + lp;
  int pos1 = (lp + 16 < 21) ? (lp + 16) : 21;
  const char* Bb = (const char*)wt + (size_t)(b * HH) * PW * CC * 2;
  size_t pxo0 = (size_t)(X0 + 1 + lp) * CC * 2;
  size_t pxo1 = (size_t)(X0 + 1 + pos1) * CC * 2;

  f32x4 acc[7][2] = {};

#pragma unroll
  for (int t = 0; t < 4; ++t) {
    bf16x8 a;
#pragma unroll
    for (int j = 0; j < 8; ++j) {
      float v = Abase[(size_t)(t * 32 + lg * 8 + j) * HWSZ];
      a[j] = f2bf(v);
    }
    size_t coff = (size_t)(t * 32 + lg * 8) * 2;
#pragma unroll
    for (int dj = 0; dj < 7; ++dj) {
      int yy = y + dj - 3;
      if (yy < 0 || yy >= HH) continue;  // wave-uniform
      const char* rb = Bb + (size_t)yy * PW * CC * 2 + coff;
      bf16x8 b0 = *(const bf16x8*)(rb + pxo0);
      bf16x8 b1 = *(const bf16x8*)(rb + pxo1);
      acc[dj][0] =
          __builtin_amdgcn_mfma_f32_16x16x32_bf16(a, b0, acc[dj][0], 0, 0, 0);
      acc[dj][1] =
          __builtin_amdgcn_mfma_f32_16x16x32_bf16(a, b1, acc[dj][1], 0, 0, 0);
    }
  }

  float* obase = out + ((size_t)(b * KK) * HH + y) * WW + X0;
#pragma unroll
  for (int dj = 0; dj < 7; ++dj) {
    float* od = obase + (size_t)(dj * 7) * HWSZ;
#pragma unroll
    for (int nt = 0; nt < 2; ++nt) {
      int post = lp + 16 * nt;
#pragma unroll
      for (int r = 0; r < 4; ++r) {
        int xlc = 4 * lg + r;
        int di = post - xlc;
        float v = acc[dj][nt][r] * (1.0f / 128.0f);
        v = (v > 0.0f) ? v : 0.1f * v;
        if (di >= 0 && di <= 6) od[(size_t)di * HWSZ + xlc] = v;
      }
    }
  }
}

// ---------------- launch ----------------------------------------------------
extern "C" void kernel_launch(void* const* d_in, const int* in_sizes, int n_in,
                              void* d_out, int out_size, void* d_ws,
                              size_t ws_size, hipStream_t stream) {
  const float* tenOne = (const float*)d_in[0];
  const float* tenTwo = (const float*)d_in[1];
  const float* tenFlow = (const float*)d_in[2];

  __hip_bfloat16* wt = (__hip_bfloat16*)d_ws;
  border_kernel<<<256, 256, 0, stream>>>(wt);

  if (ws_size >= WS_NEED) {
    __hip_bfloat16* two_t = (__hip_bfloat16*)((char*)d_ws + WT_BYTES);
    transpose_kernel<<<BB * (HWSZ / 32), 256, 0, stream>>>(tenTwo, two_t);
    warp_fast<<<512, 448, 0, stream>>>(two_t, tenFlow, wt);
  } else {
    int blocks = (BB * HWSZ + 255) / 256;
    warp_fallback<<<blocks, 256, 0, stream>>>(tenTwo, tenFlow, wt);
  }
  corr_kernel<<<3584, 256, 0, stream>>>(tenOne, wt, (float*)d_out);
}

// Round 6
// 225.386 us; speedup vs baseline: 1.7396x; 1.1918x over previous
//
#include <hip/hip_runtime.h>
#include <hip/hip_bf16.h>

// Shapes fixed by setup_inputs(): B=2, C=128, H=256, W=448, stride=1.
#define BB 2
#define CC 128
#define HH 256
#define WW 448
#define KK 49
#define HWSZ (HH * WW)
#define PW 456  // padded width of wt: px = x+4, x in [-4, 452)

#define WT_BYTES ((size_t)BB * HH * PW * CC * 2)      // 59,768,832
#define TWT_BYTES ((size_t)BB * HH * WW * CC * 2)     // 58,720,256
#define WS_NEED (WT_BYTES + TWT_BYTES)

typedef __attribute__((ext_vector_type(8))) short bf16x8;
typedef __attribute__((ext_vector_type(4))) float f32x4;
typedef __attribute__((ext_vector_type(8))) unsigned short u16x8;

static __device__ __forceinline__ short f2bf(float v) {
  __hip_bfloat16 h = __float2bfloat16(v);
  return *reinterpret_cast<short*>(&h);
}
static __device__ __forceinline__ float bf2f(unsigned short u) {
  unsigned int x = ((unsigned int)u) << 16;
  return __uint_as_float(x);
}

// ---------------- Kernel 0: zero the x-padding borders of wt ----------------
__global__ __launch_bounds__(256) void border_kernel(__hip_bfloat16* wt) {
  int i = blockIdx.x * 256 + threadIdx.x;  // 65536
  int by = i >> 7;
  int r = i & 127;
  int ps = r >> 4;
  int c16 = r & 15;
  int px = (ps < 4) ? ps : (448 + ps);
  u16x8 z = {0, 0, 0, 0, 0, 0, 0, 0};
  *(u16x8*)((char*)wt + ((size_t)((size_t)by * PW + px) * CC + c16 * 8) * 2) = z;
}

// ---------------- Kernel T: transpose tenTwo [c][p] f32 -> two_t [p][c] bf16
__global__ __launch_bounds__(256) void transpose_kernel(
    const float* __restrict__ two, __hip_bfloat16* __restrict__ two_t) {
  __shared__ float lds[128 * 33];
  int bid = blockIdx.x;            // BB * 3584
  int b = bid / (HWSZ / 32);
  int tile = bid - b * (HWSZ / 32);
  int P0 = tile * 32;

  const float* src = two + (size_t)b * CC * HWSZ + P0;
  int t = threadIdx.x;
  int bc = t >> 3;   // 0..31
  int f = t & 7;     // 0..7
#pragma unroll
  for (int k = 0; k < 4; ++k) {
    int c = bc + k * 32;
    float4 v = *(const float4*)(src + (size_t)c * HWSZ + f * 4);
    float* d = &lds[c * 33 + f * 4];
    d[0] = v.x; d[1] = v.y; d[2] = v.z; d[3] = v.w;
  }
  __syncthreads();

  int q = t & 7;     // c-chunk of 16
  int pl = t >> 3;   // 0..31 pixel
  int cs = q * 16;
  u16x8 pk0, pk1;
#pragma unroll
  for (int j = 0; j < 8; ++j)
    pk0[j] = (unsigned short)f2bf(lds[(cs + j) * 33 + pl]);
#pragma unroll
  for (int j = 0; j < 8; ++j)
    pk1[j] = (unsigned short)f2bf(lds[(cs + 8 + j) * 33 + pl]);
  char* dst = (char*)two_t + ((size_t)((size_t)b * HWSZ + P0 + pl) * CC + cs) * 2;
  *(u16x8*)dst = pk0;
  *(u16x8*)(dst + 16) = pk1;
}

// ---------------- Kernel 1 (fast): gather from two_t [p][c] bf16 -----------
__global__ __launch_bounds__(448) void warp_fast(
    const __hip_bfloat16* __restrict__ two_t, const float* __restrict__ flow,
    __hip_bfloat16* __restrict__ wt) {
  int wg = (blockIdx.x & 7) * 64 + (blockIdx.x >> 3);  // 512 blocks, bijective
  int b = wg >> 8;
  int y = wg & 255;
  int x = threadIdx.x;  // 0..447

  float fx = flow[(b * 2 + 0) * HWSZ + y * WW + x] * 2.5f;
  float fy = flow[(b * 2 + 1) * HWSZ + y * WW + x] * 2.5f;
  float px = (float)x + fx;
  float py = (float)y + fy;
  float x0f = floorf(px), y0f = floorf(py);
  int x0 = (int)x0f, y0 = (int)y0f;
  int x1 = x0 + 1, y1 = y0 + 1;
  float wx1 = px - x0f, wx0 = 1.0f - wx1;
  float wy1 = py - y0f, wy0 = 1.0f - wy1;
  bool vx0 = (x0 >= 0) && (x0 < WW);
  bool vx1 = (x1 >= 0) && (x1 < WW);
  bool vy0 = (y0 >= 0) && (y0 < HH);
  bool vy1 = (y1 >= 0) && (y1 < HH);
  float w00 = (vx0 && vy0) ? wx0 * wy0 : 0.0f;
  float w01 = (vx1 && vy0) ? wx1 * wy0 : 0.0f;
  float w10 = (vx0 && vy1) ? wx0 * wy1 : 0.0f;
  float w11 = (vx1 && vy1) ? wx1 * wy1 : 0.0f;
  int cx0 = min(max(x0, 0), WW - 1);
  int cx1 = min(max(x1, 0), WW - 1);
  int cy0 = min(max(y0, 0), HH - 1);
  int cy1 = min(max(y1, 0), HH - 1);

  const u16x8* p00 = (const u16x8*)(two_t + ((size_t)(b * HH + cy0) * WW + cx0) * CC);
  const u16x8* p01 = (const u16x8*)(two_t + ((size_t)(b * HH + cy0) * WW + cx1) * CC);
  const u16x8* p10 = (const u16x8*)(two_t + ((size_t)(b * HH + cy1) * WW + cx0) * CC);
  const u16x8* p11 = (const u16x8*)(two_t + ((size_t)(b * HH + cy1) * WW + cx1) * CC);
  u16x8* wo = (u16x8*)(wt + ((size_t)(b * HH + y) * PW + x + 4) * CC);

#pragma unroll 4
  for (int j = 0; j < 16; ++j) {
    u16x8 a = p00[j], bb_ = p01[j], c = p10[j], d = p11[j];
    u16x8 pk;
#pragma unroll
    for (int e = 0; e < 8; ++e) {
      float v = w00 * bf2f((unsigned short)a[e]) +
                w01 * bf2f((unsigned short)bb_[e]) +
                w10 * bf2f((unsigned short)c[e]) +
                w11 * bf2f((unsigned short)d[e]);
      pk[e] = (unsigned short)f2bf(v);
    }
    wo[j] = pk;
  }
}

// ---------------- Kernel 1 (fallback): gather f32 planes directly -----------
__global__ __launch_bounds__(256) void warp_fallback(
    const float* __restrict__ two, const float* __restrict__ flow,
    __hip_bfloat16* __restrict__ wt) {
  int idx = blockIdx.x * 256 + threadIdx.x;
  if (idx >= BB * HWSZ) return;
  int x = idx % WW;
  int y = (idx / WW) % HH;
  int b = idx / HWSZ;

  float fx = flow[(b * 2 + 0) * HWSZ + y * WW + x] * 2.5f;
  float fy = flow[(b * 2 + 1) * HWSZ + y * WW + x] * 2.5f;
  float px = (float)x + fx;
  float py = (float)y + fy;
  float x0f = floorf(px), y0f = floorf(py);
  int x0 = (int)x0f, y0 = (int)y0f;
  int x1 = x0 + 1, y1 = y0 + 1;
  float wx1 = px - x0f, wx0 = 1.0f - wx1;
  float wy1 = py - y0f, wy0 = 1.0f - wy1;
  bool vx0 = (x0 >= 0) && (x0 < WW);
  bool vx1 = (x1 >= 0) && (x1 < WW);
  bool vy0 = (y0 >= 0) && (y0 < HH);
  bool vy1 = (y1 >= 0) && (y1 < HH);
  float w00 = (vx0 && vy0) ? wx0 * wy0 : 0.0f;
  float w01 = (vx1 && vy0) ? wx1 * wy0 : 0.0f;
  float w10 = (vx0 && vy1) ? wx0 * wy1 : 0.0f;
  float w11 = (vx1 && vy1) ? wx1 * wy1 : 0.0f;
  int cx0 = min(max(x0, 0), WW - 1);
  int cx1 = min(max(x1, 0), WW - 1);
  int cy0 = min(max(y0, 0), HH - 1);
  int cy1 = min(max(y1, 0), HH - 1);
  int o00 = cy0 * WW + cx0;
  int o01 = cy0 * WW + cx1;
  int o10 = cy1 * WW + cx0;
  int o11 = cy1 * WW + cx1;

  const float* p = two + (size_t)b * CC * HWSZ;
  char* wo = (char*)wt + ((size_t)((size_t)(b * HH + y) * PW) + x + 4) * CC * 2;
#pragma unroll 4
  for (int j = 0; j < 16; ++j) {
    u16x8 pk;
#pragma unroll
    for (int jj = 0; jj < 8; ++jj) {
      int c = j * 8 + jj;
      const float* pc = p + (size_t)c * HWSZ;
      float v = w00 * pc[o00] + w01 * pc[o01] + w10 * pc[o10] + w11 * pc[o11];
      pk[jj] = (unsigned short)f2bf(v);
    }
    *(u16x8*)(wo + j * 16) = pk;
  }
}

// ---------------- Kernel 2: correlation via MFMA + LDS-staged B -------------
// Block = (b, ytile of 8 rows, xt of 16 px). 512 threads / 8 waves; wave w
// owns row y = ybase + w. B tile (14 rows x 22 pos x 128 ch bf16 = 77 KB)
// staged coalesced into LDS with XOR swizzle; fragments via ds_read_b128.
#define YTB 8
#define NROWS 14               // YTB + 6
#define NPOS 22
#define ROWCH (NPOS * 16)      // 352 16B-chunks per row
#define CHUNKS (NROWS * ROWCH) // 4928 chunks = 78,848 B

__global__ __launch_bounds__(512) void corr_kernel(
    const float* __restrict__ one, const __hip_bfloat16* __restrict__ wt,
    float* __restrict__ out) {
  __shared__ uint4 ldsb[CHUNKS];

  int bid = blockIdx.x;                    // 1792 = 8 * 224
  int wg = (bid & 7) * 224 + (bid >> 3);   // XCD-chunked, bijective
  int b = wg / 896;
  int rem = wg - b * 896;
  int xt = rem >> 5;   // 0..27
  int yt = rem & 31;   // 0..31
  int ybase = yt * YTB;
  int X0 = xt * 16;
  int tid = threadIdx.x;

  // ---- stage B tile (coalesced 16B chunks; zeros outside valid rows) ----
  const char* wbase =
      (const char*)wt + (((size_t)(b * HH)) * PW + X0 + 1) * (CC * 2);
#pragma unroll
  for (int k = 0; k < 10; ++k) {
    int ci = tid + k * 512;
    if (ci < CHUNKS) {
      int row = ci / ROWCH;
      int r2 = ci - row * ROWCH;
      int p = r2 >> 4;
      int cw = r2 & 15;
      int yy = ybase - 3 + row;
      uint4 v = {0, 0, 0, 0};
      if (yy >= 0 && yy < HH)
        v = *(const uint4*)(wbase + (size_t)yy * (PW * CC * 2) + p * 256 +
                            cw * 16);
      *(uint4*)((char*)ldsb + ((ci * 16) ^ ((p & 7) << 4))) = v;
    }
  }
  __syncthreads();

  int w = tid >> 6;   // wave 0..7
  int l = tid & 63;
  int lp = l & 15;
  int lg = l >> 4;
  int y = ybase + w;

  const float* Abase = one + ((size_t)(b * CC) * HH + y) * WW + X0 + lp;
  int p1 = (lp + 16 < 21) ? (lp + 16) : 21;
  int sw0 = (lp & 7) << 4;
  int sw1 = (p1 & 7) << 4;

  f32x4 acc[7][2] = {};

#pragma unroll
  for (int t = 0; t < 4; ++t) {
    bf16x8 a;
#pragma unroll
    for (int j = 0; j < 8; ++j)
      a[j] = f2bf(Abase[(size_t)(t * 32 + lg * 8 + j) * HWSZ]);
    int co = t * 64 + lg * 16;
#pragma unroll
    for (int dj = 0; dj < 7; ++dj) {
      int rl = w + dj;  // LDS row_local for yy = y + dj - 3
      int a0 = (((rl * NPOS + lp) << 8) + co) ^ sw0;
      int a1 = (((rl * NPOS + p1) << 8) + co) ^ sw1;
      bf16x8 b0 = *(const bf16x8*)((const char*)ldsb + a0);
      bf16x8 b1 = *(const bf16x8*)((const char*)ldsb + a1);
      acc[dj][0] =
          __builtin_amdgcn_mfma_f32_16x16x32_bf16(a, b0, acc[dj][0], 0, 0, 0);
      acc[dj][1] =
          __builtin_amdgcn_mfma_f32_16x16x32_bf16(a, b1, acc[dj][1], 0, 0, 0);
    }
  }

  // Epilogue: D col = lane&15 (+16*nt) = pos, row = 4*(lane>>4)+reg = x_local.
  float* obase = out + ((size_t)(b * KK) * HH + y) * WW + X0;
#pragma unroll
  for (int dj = 0; dj < 7; ++dj) {
    float* od = obase + (size_t)(dj * 7) * HWSZ;
#pragma unroll
    for (int nt = 0; nt < 2; ++nt) {
      int post = lp + 16 * nt;
#pragma unroll
      for (int r = 0; r < 4; ++r) {
        int xlc = 4 * lg + r;
        int di = post - xlc;
        float v = acc[dj][nt][r] * (1.0f / 128.0f);
        v = (v > 0.0f) ? v : 0.1f * v;
        if (di >= 0 && di <= 6) od[(size_t)di * HWSZ + xlc] = v;
      }
    }
  }
}

// ---------------- launch ----------------------------------------------------
extern "C" void kernel_launch(void* const* d_in, const int* in_sizes, int n_in,
                              void* d_out, int out_size, void* d_ws,
                              size_t ws_size, hipStream_t stream) {
  const float* tenOne = (const float*)d_in[0];
  const float* tenTwo = (const float*)d_in[1];
  const float* tenFlow = (const float*)d_in[2];

  __hip_bfloat16* wt = (__hip_bfloat16*)d_ws;
  border_kernel<<<256, 256, 0, stream>>>(wt);

  if (ws_size >= WS_NEED) {
    __hip_bfloat16* two_t = (__hip_bfloat16*)((char*)d_ws + WT_BYTES);
    transpose_kernel<<<BB * (HWSZ / 32), 256, 0, stream>>>(tenTwo, two_t);
    warp_fast<<<512, 448, 0, stream>>>(two_t, tenFlow, wt);
  } else {
    int blocks = (BB * HWSZ + 255) / 256;
    warp_fallback<<<blocks, 256, 0, stream>>>(tenTwo, tenFlow, wt);
  }
  corr_kernel<<<1792, 512, 0, stream>>>(tenOne, wt, (float*)d_out);
}

// Round 7
// 148.441 us; speedup vs baseline: 2.6413x; 1.5184x over previous
//
#include <hip/hip_runtime.h>
#include <hip/hip_bf16.h>

// Shapes fixed by setup_inputs(): B=2, C=128, H=256, W=448, stride=1.
#define BB 2
#define CC 128
#define HH 256
#define WW 448
#define KK 49
#define HWSZ (HH * WW)
#define PW 456  // padded width of wt: px = x+4, x in [-4, 452)

#define WT_BYTES ((size_t)BB * HH * PW * CC * 2)      // 59,768,832
#define TWT_BYTES ((size_t)BB * HH * WW * CC * 2)     // 58,720,256
#define WS_NEED (WT_BYTES + TWT_BYTES)

typedef __attribute__((ext_vector_type(8))) short bf16x8;
typedef __attribute__((ext_vector_type(4))) float f32x4;
typedef __attribute__((ext_vector_type(8))) unsigned short u16x8;

static __device__ __forceinline__ short f2bf(float v) {
  __hip_bfloat16 h = __float2bfloat16(v);
  return *reinterpret_cast<short*>(&h);
}
static __device__ __forceinline__ float bf2f(unsigned short u) {
  unsigned int x = ((unsigned int)u) << 16;
  return __uint_as_float(x);
}

// ---------------- Kernel 0: zero the x-padding borders of wt ----------------
__global__ __launch_bounds__(256) void border_kernel(__hip_bfloat16* wt) {
  int i = blockIdx.x * 256 + threadIdx.x;  // 65536
  int by = i >> 7;
  int r = i & 127;
  int ps = r >> 4;
  int c16 = r & 15;
  int px = (ps < 4) ? ps : (448 + ps);
  u16x8 z = {0, 0, 0, 0, 0, 0, 0, 0};
  *(u16x8*)((char*)wt + ((size_t)((size_t)by * PW + px) * CC + c16 * 8) * 2) = z;
}

// ---------------- Kernel T: transpose tenTwo [c][p] f32 -> two_t [p][c] bf16
__global__ __launch_bounds__(256) void transpose_kernel(
    const float* __restrict__ two, __hip_bfloat16* __restrict__ two_t) {
  __shared__ float lds[128 * 33];
  int bid = blockIdx.x;            // BB * 3584
  int b = bid / (HWSZ / 32);
  int tile = bid - b * (HWSZ / 32);
  int P0 = tile * 32;

  const float* src = two + (size_t)b * CC * HWSZ + P0;
  int t = threadIdx.x;
  int bc = t >> 3;   // 0..31
  int f = t & 7;     // 0..7
#pragma unroll
  for (int k = 0; k < 4; ++k) {
    int c = bc + k * 32;
    float4 v = *(const float4*)(src + (size_t)c * HWSZ + f * 4);
    float* d = &lds[c * 33 + f * 4];
    d[0] = v.x; d[1] = v.y; d[2] = v.z; d[3] = v.w;
  }
  __syncthreads();

  int q = t & 7;     // c-chunk of 16
  int pl = t >> 3;   // 0..31 pixel
  int cs = q * 16;
  u16x8 pk0, pk1;
#pragma unroll
  for (int j = 0; j < 8; ++j)
    pk0[j] = (unsigned short)f2bf(lds[(cs + j) * 33 + pl]);
#pragma unroll
  for (int j = 0; j < 8; ++j)
    pk1[j] = (unsigned short)f2bf(lds[(cs + 8 + j) * 33 + pl]);
  char* dst = (char*)two_t + ((size_t)((size_t)b * HWSZ + P0 + pl) * CC + cs) * 2;
  *(u16x8*)dst = pk0;
  *(u16x8*)(dst + 16) = pk1;
}

// ---------------- Kernel 1 (fast): gather from two_t [p][c] bf16 -----------
// Lane mapping transposed for dense lines: 16-lane group = one pixel,
// lane&15 = 16B channel chunk. Every corner read and the store are 256B
// contiguous per group -> full cache lines, no write-allocate waste.
// Block = half row (224 px), grid 1024, XCD-chunked.
__global__ __launch_bounds__(256) void warp_fast(
    const __hip_bfloat16* __restrict__ two_t, const float* __restrict__ flow,
    __hip_bfloat16* __restrict__ wt) {
  int wg = (blockIdx.x & 7) * 128 + (blockIdx.x >> 3);  // bijective, 1024
  int b = wg >> 9;
  int rem = wg & 511;
  int y = rem >> 1;
  int X0 = (rem & 1) * 224;
  int pg = threadIdx.x >> 4;  // 0..15 pixel group
  int cw = threadIdx.x & 15;  // 16B channel chunk

  const char* tb = (const char*)two_t + (size_t)b * HWSZ * (CC * 2);
  char* wb = (char*)wt + ((size_t)(b * HH + y) * PW + 4) * (CC * 2);
  const float* fxp = flow + (size_t)(b * 2 + 0) * HWSZ + y * WW;
  const float* fyp = flow + (size_t)(b * 2 + 1) * HWSZ + y * WW;

#pragma unroll 2
  for (int it = 0; it < 14; ++it) {
    int x = X0 + it * 16 + pg;

    float fx = fxp[x] * 2.5f;
    float fy = fyp[x] * 2.5f;
    float px = (float)x + fx;
    float py = (float)y + fy;
    float x0f = floorf(px), y0f = floorf(py);
    int x0 = (int)x0f, y0 = (int)y0f;
    int x1 = x0 + 1, y1 = y0 + 1;
    float wx1 = px - x0f, wx0 = 1.0f - wx1;
    float wy1 = py - y0f, wy0 = 1.0f - wy1;
    bool vx0 = (x0 >= 0) && (x0 < WW);
    bool vx1 = (x1 >= 0) && (x1 < WW);
    bool vy0 = (y0 >= 0) && (y0 < HH);
    bool vy1 = (y1 >= 0) && (y1 < HH);
    float w00 = (vx0 && vy0) ? wx0 * wy0 : 0.0f;
    float w01 = (vx1 && vy0) ? wx1 * wy0 : 0.0f;
    float w10 = (vx0 && vy1) ? wx0 * wy1 : 0.0f;
    float w11 = (vx1 && vy1) ? wx1 * wy1 : 0.0f;
    int cx0 = min(max(x0, 0), WW - 1);
    int cx1 = min(max(x1, 0), WW - 1);
    int cy0 = min(max(y0, 0), HH - 1);
    int cy1 = min(max(y1, 0), HH - 1);

    u16x8 a = *(const u16x8*)(tb + ((size_t)cy0 * WW + cx0) * 256 + cw * 16);
    u16x8 bb_ = *(const u16x8*)(tb + ((size_t)cy0 * WW + cx1) * 256 + cw * 16);
    u16x8 c = *(const u16x8*)(tb + ((size_t)cy1 * WW + cx0) * 256 + cw * 16);
    u16x8 d = *(const u16x8*)(tb + ((size_t)cy1 * WW + cx1) * 256 + cw * 16);

    u16x8 pk;
#pragma unroll
    for (int e = 0; e < 8; ++e) {
      float v = w00 * bf2f((unsigned short)a[e]) +
                w01 * bf2f((unsigned short)bb_[e]) +
                w10 * bf2f((unsigned short)c[e]) +
                w11 * bf2f((unsigned short)d[e]);
      pk[e] = (unsigned short)f2bf(v);
    }
    *(u16x8*)(wb + (size_t)x * 256 + cw * 16) = pk;
  }
}

// ---------------- Kernel 1 (fallback): gather f32 planes directly -----------
__global__ __launch_bounds__(256) void warp_fallback(
    const float* __restrict__ two, const float* __restrict__ flow,
    __hip_bfloat16* __restrict__ wt) {
  int idx = blockIdx.x * 256 + threadIdx.x;
  if (idx >= BB * HWSZ) return;
  int x = idx % WW;
  int y = (idx / WW) % HH;
  int b = idx / HWSZ;

  float fx = flow[(b * 2 + 0) * HWSZ + y * WW + x] * 2.5f;
  float fy = flow[(b * 2 + 1) * HWSZ + y * WW + x] * 2.5f;
  float px = (float)x + fx;
  float py = (float)y + fy;
  float x0f = floorf(px), y0f = floorf(py);
  int x0 = (int)x0f, y0 = (int)y0f;
  int x1 = x0 + 1, y1 = y0 + 1;
  float wx1 = px - x0f, wx0 = 1.0f - wx1;
  float wy1 = py - y0f, wy0 = 1.0f - wy1;
  bool vx0 = (x0 >= 0) && (x0 < WW);
  bool vx1 = (x1 >= 0) && (x1 < WW);
  bool vy0 = (y0 >= 0) && (y0 < HH);
  bool vy1 = (y1 >= 0) && (y1 < HH);
  float w00 = (vx0 && vy0) ? wx0 * wy0 : 0.0f;
  float w01 = (vx1 && vy0) ? wx1 * wy0 : 0.0f;
  float w10 = (vx0 && vy1) ? wx0 * wy1 : 0.0f;
  float w11 = (vx1 && vy1) ? wx1 * wy1 : 0.0f;
  int cx0 = min(max(x0, 0), WW - 1);
  int cx1 = min(max(x1, 0), WW - 1);
  int cy0 = min(max(y0, 0), HH - 1);
  int cy1 = min(max(y1, 0), HH - 1);
  int o00 = cy0 * WW + cx0;
  int o01 = cy0 * WW + cx1;
  int o10 = cy1 * WW + cx0;
  int o11 = cy1 * WW + cx1;

  const float* p = two + (size_t)b * CC * HWSZ;
  char* wo = (char*)wt + ((size_t)((size_t)(b * HH + y) * PW) + x + 4) * CC * 2;
#pragma unroll 4
  for (int j = 0; j < 16; ++j) {
    u16x8 pk;
#pragma unroll
    for (int jj = 0; jj < 8; ++jj) {
      int c = j * 8 + jj;
      const float* pc = p + (size_t)c * HWSZ;
      float v = w00 * pc[o00] + w01 * pc[o01] + w10 * pc[o10] + w11 * pc[o11];
      pk[jj] = (unsigned short)f2bf(v);
    }
    *(u16x8*)(wo + j * 16) = pk;
  }
}

// ---------------- Kernel 2: correlation via MFMA + LDS-staged B -------------
#define YTB 8
#define NROWS 14               // YTB + 6
#define NPOS 22
#define ROWCH (NPOS * 16)      // 352 16B-chunks per row
#define CHUNKS (NROWS * ROWCH) // 4928 chunks = 78,848 B

__global__ __launch_bounds__(512) void corr_kernel(
    const float* __restrict__ one, const __hip_bfloat16* __restrict__ wt,
    float* __restrict__ out) {
  __shared__ uint4 ldsb[CHUNKS];

  int bid = blockIdx.x;                    // 1792 = 8 * 224
  int wg = (bid & 7) * 224 + (bid >> 3);   // XCD-chunked, bijective
  int b = wg / 896;
  int rem = wg - b * 896;
  int xt = rem >> 5;   // 0..27
  int yt = rem & 31;   // 0..31
  int ybase = yt * YTB;
  int X0 = xt * 16;
  int tid = threadIdx.x;

  const char* wbase =
      (const char*)wt + (((size_t)(b * HH)) * PW + X0 + 1) * (CC * 2);
#pragma unroll
  for (int k = 0; k < 10; ++k) {
    int ci = tid + k * 512;
    if (ci < CHUNKS) {
      int row = ci / ROWCH;
      int r2 = ci - row * ROWCH;
      int p = r2 >> 4;
      int cw = r2 & 15;
      int yy = ybase - 3 + row;
      uint4 v = {0, 0, 0, 0};
      if (yy >= 0 && yy < HH)
        v = *(const uint4*)(wbase + (size_t)yy * (PW * CC * 2) + p * 256 +
                            cw * 16);
      *(uint4*)((char*)ldsb + ((ci * 16) ^ ((p & 7) << 4))) = v;
    }
  }
  __syncthreads();

  int w = tid >> 6;   // wave 0..7
  int l = tid & 63;
  int lp = l & 15;
  int lg = l >> 4;
  int y = ybase + w;

  const float* Abase = one + ((size_t)(b * CC) * HH + y) * WW + X0 + lp;
  int p1 = (lp + 16 < 21) ? (lp + 16) : 21;
  int sw0 = (lp & 7) << 4;
  int sw1 = (p1 & 7) << 4;

  f32x4 acc[7][2] = {};

#pragma unroll
  for (int t = 0; t < 4; ++t) {
    bf16x8 a;
#pragma unroll
    for (int j = 0; j < 8; ++j)
      a[j] = f2bf(Abase[(size_t)(t * 32 + lg * 8 + j) * HWSZ]);
    int co = t * 64 + lg * 16;
#pragma unroll
    for (int dj = 0; dj < 7; ++dj) {
      int rl = w + dj;  // LDS row_local for yy = y + dj - 3
      int a0 = (((rl * NPOS + lp) << 8) + co) ^ sw0;
      int a1 = (((rl * NPOS + p1) << 8) + co) ^ sw1;
      bf16x8 b0 = *(const bf16x8*)((const char*)ldsb + a0);
      bf16x8 b1 = *(const bf16x8*)((const char*)ldsb + a1);
      acc[dj][0] =
          __builtin_amdgcn_mfma_f32_16x16x32_bf16(a, b0, acc[dj][0], 0, 0, 0);
      acc[dj][1] =
          __builtin_amdgcn_mfma_f32_16x16x32_bf16(a, b1, acc[dj][1], 0, 0, 0);
    }
  }

  float* obase = out + ((size_t)(b * KK) * HH + y) * WW + X0;
#pragma unroll
  for (int dj = 0; dj < 7; ++dj) {
    float* od = obase + (size_t)(dj * 7) * HWSZ;
#pragma unroll
    for (int nt = 0; nt < 2; ++nt) {
      int post = lp + 16 * nt;
#pragma unroll
      for (int r = 0; r < 4; ++r) {
        int xlc = 4 * lg + r;
        int di = post - xlc;
        float v = acc[dj][nt][r] * (1.0f / 128.0f);
        v = (v > 0.0f) ? v : 0.1f * v;
        if (di >= 0 && di <= 6) od[(size_t)di * HWSZ + xlc] = v;
      }
    }
  }
}

// ---------------- launch ----------------------------------------------------
extern "C" void kernel_launch(void* const* d_in, const int* in_sizes, int n_in,
                              void* d_out, int out_size, void* d_ws,
                              size_t ws_size, hipStream_t stream) {
  const float* tenOne = (const float*)d_in[0];
  const float* tenTwo = (const float*)d_in[1];
  const float* tenFlow = (const float*)d_in[2];

  __hip_bfloat16* wt = (__hip_bfloat16*)d_ws;
  border_kernel<<<256, 256, 0, stream>>>(wt);

  if (ws_size >= WS_NEED) {
    __hip_bfloat16* two_t = (__hip_bfloat16*)((char*)d_ws + WT_BYTES);
    transpose_kernel<<<BB * (HWSZ / 32), 256, 0, stream>>>(tenTwo, two_t);
    warp_fast<<<1024, 256, 0, stream>>>(two_t, tenFlow, wt);
  } else {
    int blocks = (BB * HWSZ + 255) / 256;
    warp_fallback<<<blocks, 256, 0, stream>>>(tenTwo, tenFlow, wt);
  }
  corr_kernel<<<1792, 512, 0, stream>>>(tenOne, wt, (float*)d_out);
}

// Round 8
// 134.063 us; speedup vs baseline: 2.9246x; 1.1072x over previous
//
#include <hip/hip_runtime.h>
#include <hip/hip_bf16.h>

// Shapes fixed by setup_inputs(): B=2, C=128, H=256, W=448, stride=1.
#define BB 2
#define CC 128
#define HH 256
#define WW 448
#define KK 49
#define HWSZ (HH * WW)
#define PW 456  // padded width of wt: px = x+4, x in [-4, 452)

#define WT_BYTES ((size_t)BB * HH * PW * CC * 2)      // 59,768,832
#define TWT_BYTES ((size_t)BB * HH * WW * CC * 2)     // 58,720,256
#define WS_NEED (WT_BYTES + TWT_BYTES)

typedef __attribute__((ext_vector_type(8))) short bf16x8;
typedef __attribute__((ext_vector_type(4))) float f32x4;
typedef __attribute__((ext_vector_type(8))) unsigned short u16x8;

static __device__ __forceinline__ short f2bf(float v) {
  __hip_bfloat16 h = __float2bfloat16(v);
  return *reinterpret_cast<short*>(&h);
}
static __device__ __forceinline__ float bf2f(unsigned short u) {
  unsigned int x = ((unsigned int)u) << 16;
  return __uint_as_float(x);
}

// ---------------- Kernel 0: zero the x-padding borders of wt ----------------
__global__ __launch_bounds__(256) void border_kernel(__hip_bfloat16* wt) {
  int i = blockIdx.x * 256 + threadIdx.x;  // 65536
  int by = i >> 7;
  int r = i & 127;
  int ps = r >> 4;
  int c16 = r & 15;
  int px = (ps < 4) ? ps : (448 + ps);
  u16x8 z = {0, 0, 0, 0, 0, 0, 0, 0};
  *(u16x8*)((char*)wt + ((size_t)((size_t)by * PW + px) * CC + c16 * 8) * 2) = z;
}

// ---------------- Kernel T: transpose tenTwo [c][p] f32 -> two_t [p][c] bf16
__global__ __launch_bounds__(256) void transpose_kernel(
    const float* __restrict__ two, __hip_bfloat16* __restrict__ two_t) {
  __shared__ float lds[128 * 33];
  int bid = blockIdx.x;            // BB * 3584
  int b = bid / (HWSZ / 32);
  int tile = bid - b * (HWSZ / 32);
  int P0 = tile * 32;

  const float* src = two + (size_t)b * CC * HWSZ + P0;
  int t = threadIdx.x;
  int bc = t >> 3;   // 0..31
  int f = t & 7;     // 0..7
#pragma unroll
  for (int k = 0; k < 4; ++k) {
    int c = bc + k * 32;
    float4 v = *(const float4*)(src + (size_t)c * HWSZ + f * 4);
    float* d = &lds[c * 33 + f * 4];
    d[0] = v.x; d[1] = v.y; d[2] = v.z; d[3] = v.w;
  }
  __syncthreads();

  int q = t & 7;     // c-chunk of 16
  int pl = t >> 3;   // 0..31 pixel
  int cs = q * 16;
  u16x8 pk0, pk1;
#pragma unroll
  for (int j = 0; j < 8; ++j)
    pk0[j] = (unsigned short)f2bf(lds[(cs + j) * 33 + pl]);
#pragma unroll
  for (int j = 0; j < 8; ++j)
    pk1[j] = (unsigned short)f2bf(lds[(cs + 8 + j) * 33 + pl]);
  char* dst = (char*)two_t + ((size_t)((size_t)b * HWSZ + P0 + pl) * CC + cs) * 2;
  *(u16x8*)dst = pk0;
  *(u16x8*)(dst + 16) = pk1;
}

// ---------------- Kernel 1 (fast): gather from two_t [p][c] bf16 -----------
// 16-lane group = one pixel, lane&15 = 16B channel chunk: reads and stores
// are 256B contiguous per group (full cache lines).
__global__ __launch_bounds__(256) void warp_fast(
    const __hip_bfloat16* __restrict__ two_t, const float* __restrict__ flow,
    __hip_bfloat16* __restrict__ wt) {
  int wg = (blockIdx.x & 7) * 128 + (blockIdx.x >> 3);  // bijective, 1024
  int b = wg >> 9;
  int rem = wg & 511;
  int y = rem >> 1;
  int X0 = (rem & 1) * 224;
  int pg = threadIdx.x >> 4;  // 0..15 pixel group
  int cw = threadIdx.x & 15;  // 16B channel chunk

  const char* tb = (const char*)two_t + (size_t)b * HWSZ * (CC * 2);
  char* wb = (char*)wt + ((size_t)(b * HH + y) * PW + 4) * (CC * 2);
  const float* fxp = flow + (size_t)(b * 2 + 0) * HWSZ + y * WW;
  const float* fyp = flow + (size_t)(b * 2 + 1) * HWSZ + y * WW;

#pragma unroll 2
  for (int it = 0; it < 14; ++it) {
    int x = X0 + it * 16 + pg;

    float fx = fxp[x] * 2.5f;
    float fy = fyp[x] * 2.5f;
    float px = (float)x + fx;
    float py = (float)y + fy;
    float x0f = floorf(px), y0f = floorf(py);
    int x0 = (int)x0f, y0 = (int)y0f;
    int x1 = x0 + 1, y1 = y0 + 1;
    float wx1 = px - x0f, wx0 = 1.0f - wx1;
    float wy1 = py - y0f, wy0 = 1.0f - wy1;
    bool vx0 = (x0 >= 0) && (x0 < WW);
    bool vx1 = (x1 >= 0) && (x1 < WW);
    bool vy0 = (y0 >= 0) && (y0 < HH);
    bool vy1 = (y1 >= 0) && (y1 < HH);
    float w00 = (vx0 && vy0) ? wx0 * wy0 : 0.0f;
    float w01 = (vx1 && vy0) ? wx1 * wy0 : 0.0f;
    float w10 = (vx0 && vy1) ? wx0 * wy1 : 0.0f;
    float w11 = (vx1 && vy1) ? wx1 * wy1 : 0.0f;
    int cx0 = min(max(x0, 0), WW - 1);
    int cx1 = min(max(x1, 0), WW - 1);
    int cy0 = min(max(y0, 0), HH - 1);
    int cy1 = min(max(y1, 0), HH - 1);

    u16x8 a = *(const u16x8*)(tb + ((size_t)cy0 * WW + cx0) * 256 + cw * 16);
    u16x8 bb_ = *(const u16x8*)(tb + ((size_t)cy0 * WW + cx1) * 256 + cw * 16);
    u16x8 c = *(const u16x8*)(tb + ((size_t)cy1 * WW + cx0) * 256 + cw * 16);
    u16x8 d = *(const u16x8*)(tb + ((size_t)cy1 * WW + cx1) * 256 + cw * 16);

    u16x8 pk;
#pragma unroll
    for (int e = 0; e < 8; ++e) {
      float v = w00 * bf2f((unsigned short)a[e]) +
                w01 * bf2f((unsigned short)bb_[e]) +
                w10 * bf2f((unsigned short)c[e]) +
                w11 * bf2f((unsigned short)d[e]);
      pk[e] = (unsigned short)f2bf(v);
    }
    *(u16x8*)(wb + (size_t)x * 256 + cw * 16) = pk;
  }
}

// ---------------- Kernel 1 (fallback): gather f32 planes directly -----------
__global__ __launch_bounds__(256) void warp_fallback(
    const float* __restrict__ two, const float* __restrict__ flow,
    __hip_bfloat16* __restrict__ wt) {
  int idx = blockIdx.x * 256 + threadIdx.x;
  if (idx >= BB * HWSZ) return;
  int x = idx % WW;
  int y = (idx / WW) % HH;
  int b = idx / HWSZ;

  float fx = flow[(b * 2 + 0) * HWSZ + y * WW + x] * 2.5f;
  float fy = flow[(b * 2 + 1) * HWSZ + y * WW + x] * 2.5f;
  float px = (float)x + fx;
  float py = (float)y + fy;
  float x0f = floorf(px), y0f = floorf(py);
  int x0 = (int)x0f, y0 = (int)y0f;
  int x1 = x0 + 1, y1 = y0 + 1;
  float wx1 = px - x0f, wx0 = 1.0f - wx1;
  float wy1 = py - y0f, wy0 = 1.0f - wy1;
  bool vx0 = (x0 >= 0) && (x0 < WW);
  bool vx1 = (x1 >= 0) && (x1 < WW);
  bool vy0 = (y0 >= 0) && (y0 < HH);
  bool vy1 = (y1 >= 0) && (y1 < HH);
  float w00 = (vx0 && vy0) ? wx0 * wy0 : 0.0f;
  float w01 = (vx1 && vy0) ? wx1 * wy0 : 0.0f;
  float w10 = (vx0 && vy1) ? wx0 * wy1 : 0.0f;
  float w11 = (vx1 && vy1) ? wx1 * wy1 : 0.0f;
  int cx0 = min(max(x0, 0), WW - 1);
  int cx1 = min(max(x1, 0), WW - 1);
  int cy0 = min(max(y0, 0), HH - 1);
  int cy1 = min(max(y1, 0), HH - 1);
  int o00 = cy0 * WW + cx0;
  int o01 = cy0 * WW + cx1;
  int o10 = cy1 * WW + cx0;
  int o11 = cy1 * WW + cx1;

  const float* p = two + (size_t)b * CC * HWSZ;
  char* wo = (char*)wt + ((size_t)((size_t)(b * HH + y) * PW) + x + 4) * CC * 2;
#pragma unroll 4
  for (int j = 0; j < 16; ++j) {
    u16x8 pk;
#pragma unroll
    for (int jj = 0; jj < 8; ++jj) {
      int c = j * 8 + jj;
      const float* pc = p + (size_t)c * HWSZ;
      float v = w00 * pc[o00] + w01 * pc[o01] + w10 * pc[o10] + w11 * pc[o11];
      pk[jj] = (unsigned short)f2bf(v);
    }
    *(u16x8*)(wo + j * 16) = pk;
  }
}

// ---------------- Kernel 2: correlation via MFMA + LDS-staged B -------------
// Epilogue now LDS-transposes the banded accumulators so global stores are
// dense 64B lines (was: ~40 scattered 4B-touched lines per store instr).
#define YTB 8
#define NROWS 14               // YTB + 6
#define NPOS 22
#define ROWCH (NPOS * 16)      // 352 16B-chunks per row
#define CHUNKS (NROWS * ROWCH) // 4928 chunks = 78,848 B

__global__ __launch_bounds__(512) void corr_kernel(
    const float* __restrict__ one, const __hip_bfloat16* __restrict__ wt,
    float* __restrict__ out) {
  __shared__ uint4 ldsb[CHUNKS];

  int bid = blockIdx.x;                    // 1792 = 8 * 224
  int wg = (bid & 7) * 224 + (bid >> 3);   // XCD-chunked, bijective
  int b = wg / 896;
  int rem = wg - b * 896;
  int xt = rem >> 5;   // 0..27
  int yt = rem & 31;   // 0..31
  int ybase = yt * YTB;
  int X0 = xt * 16;
  int tid = threadIdx.x;

  const char* wbase =
      (const char*)wt + (((size_t)(b * HH)) * PW + X0 + 1) * (CC * 2);
#pragma unroll
  for (int k = 0; k < 10; ++k) {
    int ci = tid + k * 512;
    if (ci < CHUNKS) {
      int row = ci / ROWCH;
      int r2 = ci - row * ROWCH;
      int p = r2 >> 4;
      int cw = r2 & 15;
      int yy = ybase - 3 + row;
      uint4 v = {0, 0, 0, 0};
      if (yy >= 0 && yy < HH)
        v = *(const uint4*)(wbase + (size_t)yy * (PW * CC * 2) + p * 256 +
                            cw * 16);
      *(uint4*)((char*)ldsb + ((ci * 16) ^ ((p & 7) << 4))) = v;
    }
  }
  __syncthreads();

  int w = tid >> 6;   // wave 0..7
  int l = tid & 63;
  int lp = l & 15;
  int lg = l >> 4;
  int y = ybase + w;

  const float* Abase = one + ((size_t)(b * CC) * HH + y) * WW + X0 + lp;
  int p1 = (lp + 16 < 21) ? (lp + 16) : 21;
  int sw0 = (lp & 7) << 4;
  int sw1 = (p1 & 7) << 4;

  f32x4 acc[7][2] = {};

#pragma unroll
  for (int t = 0; t < 4; ++t) {
    bf16x8 a;
#pragma unroll
    for (int j = 0; j < 8; ++j)
      a[j] = f2bf(Abase[(size_t)(t * 32 + lg * 8 + j) * HWSZ]);
    int co = t * 64 + lg * 16;
#pragma unroll
    for (int dj = 0; dj < 7; ++dj) {
      int rl = w + dj;  // LDS row_local for yy = y + dj - 3
      int a0 = (((rl * NPOS + lp) << 8) + co) ^ sw0;
      int a1 = (((rl * NPOS + p1) << 8) + co) ^ sw1;
      bf16x8 b0 = *(const bf16x8*)((const char*)ldsb + a0);
      bf16x8 b1 = *(const bf16x8*)((const char*)ldsb + a1);
      acc[dj][0] =
          __builtin_amdgcn_mfma_f32_16x16x32_bf16(a, b0, acc[dj][0], 0, 0, 0);
      acc[dj][1] =
          __builtin_amdgcn_mfma_f32_16x16x32_bf16(a, b1, acc[dj][1], 0, 0, 0);
    }
  }

  // ---- Epilogue: LDS transpose -> dense stores ----
  // D layout: col = lane&15 (+16*nt) = pos, row = 4*(lane>>4)+reg = x_local.
  __syncthreads();  // all ds_reads of ldsb done; safe to reuse as scratch
  float* sc = (float*)ldsb;  // [49][8][16] f32, col-swizzled by +k (mod 16)
#pragma unroll
  for (int dj = 0; dj < 7; ++dj) {
#pragma unroll
    for (int nt = 0; nt < 2; ++nt) {
      int post = lp + 16 * nt;
#pragma unroll
      for (int r = 0; r < 4; ++r) {
        int xlc = 4 * lg + r;
        int di = post - xlc;
        if (di >= 0 && di <= 6) {
          int k = dj * 7 + di;
          sc[k * 128 + w * 16 + ((xlc + k) & 15)] = acc[dj][nt][r];
        }
      }
    }
  }
  __syncthreads();

  float* ob = out + (size_t)(b * KK) * HWSZ + (size_t)ybase * WW + X0;
#pragma unroll
  for (int i = 0; i < 13; ++i) {
    int e = tid + i * 512;
    if (e < KK * 128) {
      int k = e >> 7;
      int yr = (e >> 4) & 7;
      int px = e & 15;
      float v = sc[k * 128 + yr * 16 + ((px + k) & 15)] * (1.0f / 128.0f);
      v = (v > 0.0f) ? v : 0.1f * v;
      ob[(size_t)k * HWSZ + yr * WW + px] = v;
    }
  }
}

// ---------------- launch ----------------------------------------------------
extern "C" void kernel_launch(void* const* d_in, const int* in_sizes, int n_in,
                              void* d_out, int out_size, void* d_ws,
                              size_t ws_size, hipStream_t stream) {
  const float* tenOne = (const float*)d_in[0];
  const float* tenTwo = (const float*)d_in[1];
  const float* tenFlow = (const float*)d_in[2];

  __hip_bfloat16* wt = (__hip_bfloat16*)d_ws;
  border_kernel<<<256, 256, 0, stream>>>(wt);

  if (ws_size >= WS_NEED) {
    __hip_bfloat16* two_t = (__hip_bfloat16*)((char*)d_ws + WT_BYTES);
    transpose_kernel<<<BB * (HWSZ / 32), 256, 0, stream>>>(tenTwo, two_t);
    warp_fast<<<1024, 256, 0, stream>>>(two_t, tenFlow, wt);
  } else {
    int blocks = (BB * HWSZ + 255) / 256;
    warp_fallback<<<blocks, 256, 0, stream>>>(tenTwo, tenFlow, wt);
  }
  corr_kernel<<<1792, 512, 0, stream>>>(tenOne, wt, (float*)d_out);
}

// Round 9
// 134.039 us; speedup vs baseline: 2.9251x; 1.0002x over previous
//
#include <hip/hip_runtime.h>
#include <hip/hip_bf16.h>

// Shapes fixed by setup_inputs(): B=2, C=128, H=256, W=448, stride=1.
#define BB 2
#define CC 128
#define HH 256
#define WW 448
#define KK 49
#define HWSZ (HH * WW)
#define PW 456  // padded width of wt: px = x+4, x in [-4, 452)

#define WT_BYTES ((size_t)BB * HH * PW * CC * 2)      // 59,768,832
#define TWT_BYTES ((size_t)BB * HH * WW * CC * 2)     // 58,720,256
#define WS_NEED (WT_BYTES + TWT_BYTES)

typedef __attribute__((ext_vector_type(8))) short bf16x8;
typedef __attribute__((ext_vector_type(4))) float f32x4;
typedef __attribute__((ext_vector_type(8))) unsigned short u16x8;

static __device__ __forceinline__ short f2bf(float v) {
  __hip_bfloat16 h = __float2bfloat16(v);
  return *reinterpret_cast<short*>(&h);
}
static __device__ __forceinline__ float bf2f(unsigned short u) {
  unsigned int x = ((unsigned int)u) << 16;
  return __uint_as_float(x);
}

// ---------------- Kernel 0: zero the x-padding borders of wt ----------------
__global__ __launch_bounds__(256) void border_kernel(__hip_bfloat16* wt) {
  int i = blockIdx.x * 256 + threadIdx.x;  // 65536
  int by = i >> 7;
  int r = i & 127;
  int ps = r >> 4;
  int c16 = r & 15;
  int px = (ps < 4) ? ps : (448 + ps);
  u16x8 z = {0, 0, 0, 0, 0, 0, 0, 0};
  *(u16x8*)((char*)wt + ((size_t)((size_t)by * PW + px) * CC + c16 * 8) * 2) = z;
}

// ---------------- Kernel T: transpose tenTwo [c][p] f32 -> two_t [p][c] bf16
__global__ __launch_bounds__(256) void transpose_kernel(
    const float* __restrict__ two, __hip_bfloat16* __restrict__ two_t) {
  __shared__ float lds[128 * 33];
  int bid = blockIdx.x;            // BB * 3584
  int b = bid / (HWSZ / 32);
  int tile = bid - b * (HWSZ / 32);
  int P0 = tile * 32;

  const float* src = two + (size_t)b * CC * HWSZ + P0;
  int t = threadIdx.x;
  int bc = t >> 3;   // 0..31
  int f = t & 7;     // 0..7
#pragma unroll
  for (int k = 0; k < 4; ++k) {
    int c = bc + k * 32;
    float4 v = *(const float4*)(src + (size_t)c * HWSZ + f * 4);
    float* d = &lds[c * 33 + f * 4];
    d[0] = v.x; d[1] = v.y; d[2] = v.z; d[3] = v.w;
  }
  __syncthreads();

  int q = t & 7;     // c-chunk of 16
  int pl = t >> 3;   // 0..31 pixel
  int cs = q * 16;
  u16x8 pk0, pk1;
#pragma unroll
  for (int j = 0; j < 8; ++j)
    pk0[j] = (unsigned short)f2bf(lds[(cs + j) * 33 + pl]);
#pragma unroll
  for (int j = 0; j < 8; ++j)
    pk1[j] = (unsigned short)f2bf(lds[(cs + 8 + j) * 33 + pl]);
  char* dst = (char*)two_t + ((size_t)((size_t)b * HWSZ + P0 + pl) * CC + cs) * 2;
  *(u16x8*)dst = pk0;
  *(u16x8*)(dst + 16) = pk1;
}

// ---------------- Kernel 1 (fast): gather from two_t [p][c] bf16 -----------
// 16-lane group = one pixel, lane&15 = 16B channel chunk: reads and stores
// are 256B contiguous per group (full cache lines).
__global__ __launch_bounds__(256) void warp_fast(
    const __hip_bfloat16* __restrict__ two_t, const float* __restrict__ flow,
    __hip_bfloat16* __restrict__ wt) {
  int wg = (blockIdx.x & 7) * 128 + (blockIdx.x >> 3);  // bijective, 1024
  int b = wg >> 9;
  int rem = wg & 511;
  int y = rem >> 1;
  int X0 = (rem & 1) * 224;
  int pg = threadIdx.x >> 4;  // 0..15 pixel group
  int cw = threadIdx.x & 15;  // 16B channel chunk

  const char* tb = (const char*)two_t + (size_t)b * HWSZ * (CC * 2);
  char* wb = (char*)wt + ((size_t)(b * HH + y) * PW + 4) * (CC * 2);
  const float* fxp = flow + (size_t)(b * 2 + 0) * HWSZ + y * WW;
  const float* fyp = flow + (size_t)(b * 2 + 1) * HWSZ + y * WW;

#pragma unroll 2
  for (int it = 0; it < 14; ++it) {
    int x = X0 + it * 16 + pg;

    float fx = fxp[x] * 2.5f;
    float fy = fyp[x] * 2.5f;
    float px = (float)x + fx;
    float py = (float)y + fy;
    float x0f = floorf(px), y0f = floorf(py);
    int x0 = (int)x0f, y0 = (int)y0f;
    int x1 = x0 + 1, y1 = y0 + 1;
    float wx1 = px - x0f, wx0 = 1.0f - wx1;
    float wy1 = py - y0f, wy0 = 1.0f - wy1;
    bool vx0 = (x0 >= 0) && (x0 < WW);
    bool vx1 = (x1 >= 0) && (x1 < WW);
    bool vy0 = (y0 >= 0) && (y0 < HH);
    bool vy1 = (y1 >= 0) && (y1 < HH);
    float w00 = (vx0 && vy0) ? wx0 * wy0 : 0.0f;
    float w01 = (vx1 && vy0) ? wx1 * wy0 : 0.0f;
    float w10 = (vx0 && vy1) ? wx0 * wy1 : 0.0f;
    float w11 = (vx1 && vy1) ? wx1 * wy1 : 0.0f;
    int cx0 = min(max(x0, 0), WW - 1);
    int cx1 = min(max(x1, 0), WW - 1);
    int cy0 = min(max(y0, 0), HH - 1);
    int cy1 = min(max(y1, 0), HH - 1);

    u16x8 a = *(const u16x8*)(tb + ((size_t)cy0 * WW + cx0) * 256 + cw * 16);
    u16x8 bb_ = *(const u16x8*)(tb + ((size_t)cy0 * WW + cx1) * 256 + cw * 16);
    u16x8 c = *(const u16x8*)(tb + ((size_t)cy1 * WW + cx0) * 256 + cw * 16);
    u16x8 d = *(const u16x8*)(tb + ((size_t)cy1 * WW + cx1) * 256 + cw * 16);

    u16x8 pk;
#pragma unroll
    for (int e = 0; e < 8; ++e) {
      float v = w00 * bf2f((unsigned short)a[e]) +
                w01 * bf2f((unsigned short)bb_[e]) +
                w10 * bf2f((unsigned short)c[e]) +
                w11 * bf2f((unsigned short)d[e]);
      pk[e] = (unsigned short)f2bf(v);
    }
    *(u16x8*)(wb + (size_t)x * 256 + cw * 16) = pk;
  }
}

// ---------------- Kernel 1 (fallback): gather f32 planes directly -----------
__global__ __launch_bounds__(256) void warp_fallback(
    const float* __restrict__ two, const float* __restrict__ flow,
    __hip_bfloat16* __restrict__ wt) {
  int idx = blockIdx.x * 256 + threadIdx.x;
  if (idx >= BB * HWSZ) return;
  int x = idx % WW;
  int y = (idx / WW) % HH;
  int b = idx / HWSZ;

  float fx = flow[(b * 2 + 0) * HWSZ + y * WW + x] * 2.5f;
  float fy = flow[(b * 2 + 1) * HWSZ + y * WW + x] * 2.5f;
  float px = (float)x + fx;
  float py = (float)y + fy;
  float x0f = floorf(px), y0f = floorf(py);
  int x0 = (int)x0f, y0 = (int)y0f;
  int x1 = x0 + 1, y1 = y0 + 1;
  float wx1 = px - x0f, wx0 = 1.0f - wx1;
  float wy1 = py - y0f, wy0 = 1.0f - wy1;
  bool vx0 = (x0 >= 0) && (x0 < WW);
  bool vx1 = (x1 >= 0) && (x1 < WW);
  bool vy0 = (y0 >= 0) && (y0 < HH);
  bool vy1 = (y1 >= 0) && (y1 < HH);
  float w00 = (vx0 && vy0) ? wx0 * wy0 : 0.0f;
  float w01 = (vx1 && vy0) ? wx1 * wy0 : 0.0f;
  float w10 = (vx0 && vy1) ? wx0 * wy1 : 0.0f;
  float w11 = (vx1 && vy1) ? wx1 * wy1 : 0.0f;
  int cx0 = min(max(x0, 0), WW - 1);
  int cx1 = min(max(x1, 0), WW - 1);
  int cy0 = min(max(y0, 0), HH - 1);
  int cy1 = min(max(y1, 0), HH - 1);
  int o00 = cy0 * WW + cx0;
  int o01 = cy0 * WW + cx1;
  int o10 = cy1 * WW + cx0;
  int o11 = cy1 * WW + cx1;

  const float* p = two + (size_t)b * CC * HWSZ;
  char* wo = (char*)wt + ((size_t)((size_t)(b * HH + y) * PW) + x + 4) * CC * 2;
#pragma unroll 4
  for (int j = 0; j < 16; ++j) {
    u16x8 pk;
#pragma unroll
    for (int jj = 0; jj < 8; ++jj) {
      int c = j * 8 + jj;
      const float* pc = p + (size_t)c * HWSZ;
      float v = w00 * pc[o00] + w01 * pc[o01] + w10 * pc[o10] + w11 * pc[o11];
      pk[jj] = (unsigned short)f2bf(v);
    }
    *(u16x8*)(wo + j * 16) = pk;
  }
}

// ---------------- Kernel 2: correlation via MFMA + LDS-staged B -------------
// Latency-flattened: all staging loads + all A loads issued up-front into
// registers; one barrier; compute phase is pure ds_read_b128 + MFMA.
#define YTB 8
#define NROWS 14               // YTB + 6
#define NPOS 22
#define ROWCH (NPOS * 16)      // 352 16B-chunks per row
#define CHUNKS (NROWS * ROWCH) // 4928 chunks = 78,848 B

__global__ __launch_bounds__(512, 4) void corr_kernel(
    const float* __restrict__ one, const __hip_bfloat16* __restrict__ wt,
    float* __restrict__ out) {
  __shared__ uint4 ldsb[CHUNKS];

  int bid = blockIdx.x;                    // 1792 = 8 * 224
  int wg = (bid & 7) * 224 + (bid >> 3);   // XCD-chunked, bijective
  int b = wg / 896;
  int rem = wg - b * 896;
  int xt = rem >> 5;   // 0..27
  int yt = rem & 31;   // 0..31
  int ybase = yt * YTB;
  int X0 = xt * 16;
  int tid = threadIdx.x;

  int w = tid >> 6;   // wave 0..7
  int l = tid & 63;
  int lp = l & 15;
  int lg = l >> 4;
  int y = ybase + w;

  // ---- Phase 1: issue all staging loads into registers (longest latency) --
  const char* wbase =
      (const char*)wt + (((size_t)(b * HH)) * PW + X0 + 1) * (CC * 2);
  uint4 sv[10];
  int lofs[10];
#pragma unroll
  for (int k = 0; k < 10; ++k) {
    int ci = tid + k * 512;
    int row = ci / ROWCH;
    int r2 = ci - row * ROWCH;
    int p = r2 >> 4;
    int cw = r2 & 15;
    int yy = ybase - 3 + row;
    uint4 v = {0, 0, 0, 0};
    if (ci < CHUNKS && yy >= 0 && yy < HH)
      v = *(const uint4*)(wbase + (size_t)yy * (PW * CC * 2) + p * 256 +
                          cw * 16);
    sv[k] = v;
    lofs[k] = (ci * 16) ^ ((p & 7) << 4);
  }

  // ---- Phase 2: all A loads + convert to bf16 fragments -------------------
  const float* Abase = one + ((size_t)(b * CC) * HH + y) * WW + X0 + lp;
  float af[32];
#pragma unroll
  for (int t = 0; t < 4; ++t)
#pragma unroll
    for (int j = 0; j < 8; ++j)
      af[t * 8 + j] = Abase[(size_t)(t * 32 + lg * 8 + j) * HWSZ];
  bf16x8 afr[4];
#pragma unroll
  for (int t = 0; t < 4; ++t)
#pragma unroll
    for (int j = 0; j < 8; ++j) afr[t][j] = f2bf(af[t * 8 + j]);

  // ---- Phase 3: write staged chunks to LDS (swizzled), one barrier --------
#pragma unroll
  for (int k = 0; k < 10; ++k)
    if (tid + k * 512 < CHUNKS) *(uint4*)((char*)ldsb + lofs[k]) = sv[k];
  __syncthreads();

  // ---- Phase 4: pure ds_read + MFMA ---------------------------------------
  int p1 = (lp + 16 < 21) ? (lp + 16) : 21;
  int cosw0[4], cosw1[4];
#pragma unroll
  for (int t = 0; t < 4; ++t) {
    int co = t * 64 + lg * 16;
    cosw0[t] = co ^ ((lp & 7) << 4);
    cosw1[t] = co ^ ((p1 & 7) << 4);
  }

  f32x4 acc[7][2] = {};
#pragma unroll
  for (int dj = 0; dj < 7; ++dj) {
    int rl = w + dj;  // LDS row_local for yy = y + dj - 3
    int b0 = (rl * NPOS + lp) << 8;
    int b1 = (rl * NPOS + p1) << 8;
#pragma unroll
    for (int t = 0; t < 4; ++t) {
      bf16x8 v0 = *(const bf16x8*)((const char*)ldsb + (b0 + cosw0[t]));
      bf16x8 v1 = *(const bf16x8*)((const char*)ldsb + (b1 + cosw1[t]));
      acc[dj][0] =
          __builtin_amdgcn_mfma_f32_16x16x32_bf16(afr[t], v0, acc[dj][0], 0, 0, 0);
      acc[dj][1] =
          __builtin_amdgcn_mfma_f32_16x16x32_bf16(afr[t], v1, acc[dj][1], 0, 0, 0);
    }
  }

  // ---- Epilogue: LDS transpose -> dense stores ----------------------------
  // D layout: col = lane&15 (+16*nt) = pos, row = 4*(lane>>4)+reg = x_local.
  __syncthreads();  // all ds_reads of ldsb done; safe to reuse as scratch
  float* sc = (float*)ldsb;  // [49][8][16] f32, col-swizzled by +k (mod 16)
#pragma unroll
  for (int dj = 0; dj < 7; ++dj) {
#pragma unroll
    for (int nt = 0; nt < 2; ++nt) {
      int post = lp + 16 * nt;
#pragma unroll
      for (int r = 0; r < 4; ++r) {
        int xlc = 4 * lg + r;
        int di = post - xlc;
        if (di >= 0 && di <= 6) {
          int k = dj * 7 + di;
          sc[k * 128 + w * 16 + ((xlc + k) & 15)] = acc[dj][nt][r];
        }
      }
    }
  }
  __syncthreads();

  float* ob = out + (size_t)(b * KK) * HWSZ + (size_t)ybase * WW + X0;
#pragma unroll
  for (int i = 0; i < 13; ++i) {
    int e = tid + i * 512;
    if (e < KK * 128) {
      int k = e >> 7;
      int yr = (e >> 4) & 7;
      int px = e & 15;
      float v = sc[k * 128 + yr * 16 + ((px + k) & 15)] * (1.0f / 128.0f);
      v = (v > 0.0f) ? v : 0.1f * v;
      ob[(size_t)k * HWSZ + yr * WW + px] = v;
    }
  }
}

// ---------------- launch ----------------------------------------------------
extern "C" void kernel_launch(void* const* d_in, const int* in_sizes, int n_in,
                              void* d_out, int out_size, void* d_ws,
                              size_t ws_size, hipStream_t stream) {
  const float* tenOne = (const float*)d_in[0];
  const float* tenTwo = (const float*)d_in[1];
  const float* tenFlow = (const float*)d_in[2];

  __hip_bfloat16* wt = (__hip_bfloat16*)d_ws;
  border_kernel<<<256, 256, 0, stream>>>(wt);

  if (ws_size >= WS_NEED) {
    __hip_bfloat16* two_t = (__hip_bfloat16*)((char*)d_ws + WT_BYTES);
    transpose_kernel<<<BB * (HWSZ / 32), 256, 0, stream>>>(tenTwo, two_t);
    warp_fast<<<1024, 256, 0, stream>>>(two_t, tenFlow, wt);
  } else {
    int blocks = (BB * HWSZ + 255) / 256;
    warp_fallback<<<blocks, 256, 0, stream>>>(tenTwo, tenFlow, wt);
  }
  corr_kernel<<<1792, 512, 0, stream>>>(tenOne, wt, (float*)d_out);
}